// Round 6
// baseline (127.495 us; speedup 1.0000x reference)
//
#include <hip/hip_runtime.h>

// Shapes: B=16, N=32 (512 targets), NS=3 scales, NA=3 anchors, NC=80.
// Grids 64/32/16. Cells per scale = 16*3*g*g.
constexpr int S0 = 16 * 3 * 64 * 64;  // 196608
constexpr int S1 = 16 * 3 * 32 * 32;  // 49152
constexpr int S2 = 16 * 3 * 16 * 16;  // 12288
constexpr int TOT = S0 + S1 + S2;     // 258048

// Grid layout (single dispatch, 256 threads/block):
//   [0, TBLOCKS)                  target path, one WAVE per target
//   [TBLOCKS, TBLOCKS+DBLOCKS)    dense obj baseline, 2048 cells/block
//   [NPROD]                       finalizer (spins on flags, reduces, writes)
constexpr int TBLOCKS = 512 / 4;         // 128
constexpr int DBLOCKS = TOT / 2048;      // 126
constexpr int DB0 = S0 / 2048;           // 96
constexpr int DB1 = DB0 + S1 / 2048;     // 120
constexpr int NPROD = TBLOCKS + DBLOCKS; // 254

// ws layout: float rows[NPROD][16]; then uint flags[NPROD].
// Rows: target blocks fill cols 0..9; dense blocks fill col 0 only.
// Flags: release-stored 1 when the block's row is visible. Poison is
// 0xAAAAAAAA != 1, so no zero-init dispatch is needed.
constexpr int WS_FLAGS = NPROD * 16;

__device__ __forceinline__ float softplusf(float x) {
    return fmaxf(x, 0.0f) + __logf(1.0f + __expf(-fabsf(x)));
}

// Anchor-IoU hit test. Single definition so the wave's own test and the
// earlier-target dedupe test are bit-exact identical.
__device__ __forceinline__ bool anchor_hit(
    float x, float y, float w, float h, float st, float aw, float ah,
    int& ci, int& cj, float& fx, float& fy, float& tbw, float& tbh)
{
    const float tbx = x / st, tby = y / st;
    tbw = w / st; tbh = h / st;
    const float cif = floorf(tbx), cjf = floorf(tby);
    ci = (int)cif; cj = (int)cjf;
    fx = tbx - cif; fy = tby - cjf;
    const float tx0 = fx - tbw*0.5f, ty0 = fy - tbh*0.5f;
    const float tx1 = fx + tbw*0.5f, ty1 = fy + tbh*0.5f;
    const float ax0 = 0.5f - aw*0.5f, ay0 = 0.5f - ah*0.5f;
    const float ax1 = 0.5f + aw*0.5f, ay1 = 0.5f + ah*0.5f;
    const float ix0 = fmaxf(tx0, ax0), iy0 = fmaxf(ty0, ay0);
    const float ix1 = fminf(tx1, ax1), iy1 = fminf(ty1, ay1);
    float inter = (ix1-ix0)*(iy1-iy0);
    inter = (ix0 < ix1 && iy0 < iy1) ? inter : 0.0f;
    const float iou = inter / (tbw*tbh + aw*ah - inter);
    return iou > 0.5f;
}

__device__ __forceinline__ void publish_row(float* __restrict__ ws,
                                            const float* row10, int bi,
                                            int tid) {
    // tid<10 threads hold row10 values by convention of the caller.
    if (tid < 10) ws[bi * 16 + tid] = row10[0];
    __syncthreads();
    if (tid == 0) {
        __threadfence();  // device scope: row visible before flag
        unsigned int* flags = (unsigned int*)ws + WS_FLAGS;
        __hip_atomic_store(&flags[bi], 1u, __ATOMIC_RELEASE,
                           __HIP_MEMORY_SCOPE_AGENT);
    }
}

__global__ __launch_bounds__(256) void yolo_fused_kernel(
    const float* __restrict__ inf0, const float* __restrict__ inf1,
    const float* __restrict__ inf2, const float* __restrict__ anchors,
    const float* __restrict__ strides, const float* __restrict__ targets,
    float* __restrict__ ws, float* __restrict__ out)
{
    const int tid = threadIdx.x;

    if (blockIdx.x < TBLOCKS) {
        // ---------------- target path: one wave per target -----------------
        const int tb   = blockIdx.x;
        const int wid  = tid >> 6;
        const int lane = tid & 63;
        const int t    = tb * 4 + wid;   // 0..511
        const int b    = t >> 5;

        const float x = targets[t*5+0];
        const float y = targets[t*5+1];
        const float w = targets[t*5+2];
        const float h = targets[t*5+3];
        const int cls = (int)targets[t*5+4];

        // ---- phase 1: all 9 hit tests + issue pred loads (max MLP) ----
        bool  hit[9];
        int   vci[9], vcj[9];
        float vfx[9], vfy[9], vtw[9], vth[9], vaw[9], vah[9];
        float r0[9], r1[9];
        #pragma unroll
        for (int sa = 0; sa < 9; ++sa) {
            const int s = sa / 3, a = sa - 3 * (sa / 3);
            const float st = strides[s];
            const float aw = anchors[(s*3+a)*2+0] / st;
            const float ah = anchors[(s*3+a)*2+1] / st;
            vaw[sa] = aw; vah[sa] = ah;
            hit[sa] = anchor_hit(x, y, w, h, st, aw, ah, vci[sa], vcj[sa],
                                 vfx[sa], vfy[sa], vtw[sa], vth[sa]);
            r0[sa] = 0.0f; r1[sa] = 0.0f;
            if (hit[sa]) {  // wave-uniform branch
                const int g = (s == 0) ? 64 : (s == 1) ? 32 : 16;
                const float* inf = (s == 0) ? inf0 : (s == 1) ? inf1 : inf2;
                const int cellflat = ((b*3 + a)*g + vcj[sa])*g + vci[sa];
                const float* pred = inf + (long)cellflat * 85;
                r0[sa] = pred[lane];                      // ch 0..63
                if (lane < 21) r1[sa] = pred[64 + lane];  // ch 64..84
            }
        }

        // ---- phase 2: consume ----
        float acc[10];
        #pragma unroll
        for (int c = 0; c < 10; ++c) acc[c] = 0.0f;

        #pragma unroll
        for (int sa = 0; sa < 9; ++sa) {
            if (!hit[sa]) continue;
            const int s = sa / 3;
            const float st = strides[s];
            const float invM = (s == 0) ? 1.0f/(float)S0
                             : (s == 1) ? 1.0f/(float)S1 : 1.0f/(float)S2;
            const float aw = vaw[sa], ah = vah[sa];
            const float fx = vfx[sa], fy = vfy[sa];
            const float tbw = vtw[sa], tbh = vth[sa];

            const float p0 = __shfl(r0[sa], 0, 64);
            const float p1 = __shfl(r0[sa], 1, 64);
            const float p2 = __shfl(r0[sa], 2, 64);
            const float p3 = __shfl(r0[sa], 3, 64);
            const float p4 = __shfl(r0[sa], 4, 64);

            // box term
            const float px = 1.0f / (1.0f + __expf(-p0));
            const float py = 1.0f / (1.0f + __expf(-p1));
            const float pw = fminf(__expf(p2), 1000.0f) * aw;
            const float ph = fminf(__expf(p3), 1000.0f) * ah;
            const float tx0 = fx - tbw*0.5f, ty0 = fy - tbh*0.5f;
            const float tx1 = fx + tbw*0.5f, ty1 = fy + tbh*0.5f;
            const float bx0 = px - pw*0.5f, by0 = py - ph*0.5f;
            const float bx1 = px + pw*0.5f, by1 = py + ph*0.5f;
            const float jx0 = fmaxf(bx0, tx0), jy0 = fmaxf(by0, ty0);
            const float jx1 = fminf(bx1, tx1), jy1 = fminf(by1, ty1);
            float inter2 = (jx1-jx0)*(jy1-jy0);
            inter2 = (jx0 < jx1 && jy0 < jy1) ? inter2 : 0.0f;
            const float iou2 = inter2 / (pw*ph + tbw*tbh - inter2);

            // cls term: lanes 5..63 cover classes 0..58 via r0 (ch=lane),
            // lanes 0..20 cover classes 59..79 via r1 (ch=64+lane).
            float v = 0.0f;
            if (lane >= 5) {
                v += softplusf(r0[sa]);
                if (lane == 5 + cls) v -= r0[sa];
            }
            if (lane < 21) {
                v += softplusf(r1[sa]);
                if (59 + lane == cls) v -= r1[sa];
            }
            #pragma unroll
            for (int off = 32; off > 0; off >>= 1)
                v += __shfl_down(v, off, 64);

            // t_obj dedupe: claim iff NO earlier target t'<t in this batch
            // hits the same (ci,cj) at this (s,a) — bit-exact anchor_hit.
            bool dup = false;
            if (lane < (t & 31)) {
                const int t2 = (b << 5) + lane;
                const float x2 = targets[t2*5+0];
                const float y2 = targets[t2*5+1];
                const float w2 = targets[t2*5+2];
                const float h2 = targets[t2*5+3];
                int ci2, cj2; float fx2, fy2, tbw2, tbh2;
                const bool hit2 = anchor_hit(x2, y2, w2, h2, st, aw, ah,
                                             ci2, cj2, fx2, fy2, tbw2, tbh2);
                dup = hit2 && (ci2 == vci[sa]) && (cj2 == vcj[sa]);
            }
            const unsigned long long m = __ballot(dup);

            acc[1 + s] += 1.0f;
            acc[4 + s] += 1.0f - iou2;
            acc[7 + s] += v;           // lane 0 holds the reduced value
            if (m == 0ull) acc[0] += -p4 * invM;
        }

        // combine the 4 waves' rows (lane 0 of each holds valid acc)
        __shared__ float rows[4][10];
        if (lane == 0) {
            #pragma unroll
            for (int c = 0; c < 10; ++c) rows[wid][c] = acc[c];
        }
        __syncthreads();
        float myrow = 0.0f;
        if (tid < 10)
            myrow = rows[0][tid] + rows[1][tid] + rows[2][tid] + rows[3][tid];
        publish_row(ws, &myrow, blockIdx.x, tid);

    } else if (blockIdx.x < NPROD) {
        // ---------------- dense obj baseline: 2048 scale-pure cells --------
        const int bi = blockIdx.x - TBLOCKS;
        const float* inf; int base; float w;
        if (bi < DB0)      { inf = inf0; base = bi * 2048;          w = 1.0f/(float)S0; }
        else if (bi < DB1) { inf = inf1; base = (bi - DB0) * 2048;  w = 1.0f/(float)S1; }
        else               { inf = inf2; base = (bi - DB1) * 2048;  w = 1.0f/(float)S2; }
        const int l0 = base + tid;
        float v = 0.0f;
        #pragma unroll
        for (int k = 0; k < 8; ++k)
            v += softplusf(inf[(long)(l0 + k * 256) * 85 + 4]);
        #pragma unroll
        for (int off = 32; off > 0; off >>= 1) v += __shfl_down(v, off, 64);
        __shared__ float wsum[4];
        const int lane = tid & 63, wid = tid >> 6;
        if (lane == 0) wsum[wid] = v;
        __syncthreads();
        float myrow = 0.0f;
        if (tid == 0) myrow = (wsum[0] + wsum[1] + wsum[2] + wsum[3]) * w;
        // cols 1..9 must be 0 for dense rows
        publish_row(ws, &myrow, blockIdx.x, tid);

    } else {
        // ---------------- finalizer: spin on flags, reduce, emit -----------
        unsigned int* flags = (unsigned int*)ws + WS_FLAGS;
        if (tid < NPROD) {
            while (__hip_atomic_load(&flags[tid], __ATOMIC_ACQUIRE,
                                     __HIP_MEMORY_SCOPE_AGENT) != 1u) {
                __builtin_amdgcn_s_sleep(1);
            }
        }
        __syncthreads();

        float acc[10];
        #pragma unroll
        for (int c = 0; c < 10; ++c) acc[c] = 0.0f;
        for (int r = tid; r < NPROD; r += 256) {
            #pragma unroll
            for (int c = 0; c < 10; ++c) acc[c] += ws[r * 16 + c];
        }
        #pragma unroll
        for (int c = 0; c < 10; ++c) {
            float v = acc[c];
            #pragma unroll
            for (int off = 32; off > 0; off >>= 1)
                v += __shfl_down(v, off, 64);
            acc[c] = v;
        }
        __shared__ float red[4][10];
        const int lane = tid & 63, wid = tid >> 6;
        if (lane == 0) {
            #pragma unroll
            for (int c = 0; c < 10; ++c) red[wid][c] = acc[c];
        }
        __syncthreads();
        if (tid == 0) {
            float tt[10];
            #pragma unroll
            for (int c = 0; c < 10; ++c)
                tt[c] = red[0][c] + red[1][c] + red[2][c] + red[3][c];
            float box = 0.0f, cls = 0.0f;
            #pragma unroll
            for (int s = 0; s < 3; ++s) {
                const float cnt = fmaxf(tt[1 + s], 1.0f);
                box += tt[4 + s] / cnt;
                cls += tt[7 + s] / (cnt * 80.0f);
            }
            out[0] = 3.54f * box + 64.3f * tt[0] + 37.4f * cls;
        }
    }
}

extern "C" void kernel_launch(void* const* d_in, const int* in_sizes, int n_in,
                              void* d_out, int out_size, void* d_ws, size_t ws_size,
                              hipStream_t stream) {
    const float* inf0    = (const float*)d_in[0];
    const float* inf1    = (const float*)d_in[1];
    const float* inf2    = (const float*)d_in[2];
    const float* anchors = (const float*)d_in[3];
    const float* strides = (const float*)d_in[4];
    const float* targets = (const float*)d_in[5];
    float* ws  = (float*)d_ws;
    float* out = (float*)d_out;

    yolo_fused_kernel<<<NPROD + 1, 256, 0, stream>>>(
        inf0, inf1, inf2, anchors, strides, targets, ws, out);
}

// Round 7
// 112.974 us; speedup vs baseline: 1.1285x; 1.1285x over previous
//
#include <hip/hip_runtime.h>

// Shapes: B=16, N=32 (512 targets), NS=3 scales, NA=3 anchors, NC=80.
// Grids 64/32/16. Cells per scale = 16*3*g*g.
//
// R6 lesson (do NOT refuse this): single-dispatch producer->consumer fusion
// with per-block __threadfence + agent-scope release flags regressed +15us.
// Per-XCD L2s are not cross-coherent on MI355X, so every producer block's
// fence pays an L2 writeback toward the coherence point; the kernel boundary
// between the two dispatches below does that flush ONCE. Keep 2 dispatches.
constexpr int S0 = 16 * 3 * 64 * 64;  // 196608
constexpr int S1 = 16 * 3 * 32 * 32;  // 49152
constexpr int S2 = 16 * 3 * 16 * 16;  // 12288
constexpr int TOT = S0 + S1 + S2;     // 258048

// Dense obj path: 8 cells/thread, 2048 cells/block -> scale-pure blocks.
constexpr int DBLOCKS = TOT / 2048;   // 126
constexpr int DB0 = S0 / 2048;        // 96
constexpr int DB1 = DB0 + S1 / 2048;  // 120

// Target path: one WAVE per target, 4 waves/block -> 128 blocks.
constexpr int TBLOCKS = 512 / 4;      // 128

// ws layout (floats): [0, TBLOCKS*10)           target-block partial rows
//                     [WS_OBJ, WS_OBJ+DBLOCKS)  dense obj partials
constexpr int WS_OBJ = TBLOCKS * 10;  // 1280

__device__ __forceinline__ float softplusf(float x) {
    return fmaxf(x, 0.0f) + __logf(1.0f + __expf(-fabsf(x)));
}

// Anchor-IoU hit test. Single definition so the wave's own test and the
// earlier-target dedupe test are bit-exact identical.
__device__ __forceinline__ bool anchor_hit(
    float x, float y, float w, float h, float st, float aw, float ah,
    int& ci, int& cj, float& fx, float& fy, float& tbw, float& tbh)
{
    const float tbx = x / st, tby = y / st;
    tbw = w / st; tbh = h / st;
    const float cif = floorf(tbx), cjf = floorf(tby);
    ci = (int)cif; cj = (int)cjf;
    fx = tbx - cif; fy = tby - cjf;
    const float tx0 = fx - tbw*0.5f, ty0 = fy - tbh*0.5f;
    const float tx1 = fx + tbw*0.5f, ty1 = fy + tbh*0.5f;
    const float ax0 = 0.5f - aw*0.5f, ay0 = 0.5f - ah*0.5f;
    const float ax1 = 0.5f + aw*0.5f, ay1 = 0.5f + ah*0.5f;
    const float ix0 = fmaxf(tx0, ax0), iy0 = fmaxf(ty0, ay0);
    const float ix1 = fminf(tx1, ax1), iy1 = fminf(ty1, ay1);
    float inter = (ix1-ix0)*(iy1-iy0);
    inter = (ix0 < ix1 && iy0 < iy1) ? inter : 0.0f;
    const float iou = inter / (tbw*tbh + aw*ah - inter);
    return iou > 0.5f;
}

// K1 (fused, 254 blocks total):
//   blocks [0, DBLOCKS)              dense obj baseline, 2048 cells/block
//   blocks [DBLOCKS, DBLOCKS+128)    one wave per target, 9 (s,a) unrolled
// No global atomics; each block writes partials to a private ws slot.
__global__ __launch_bounds__(256) void yolo_main_kernel(
    const float* __restrict__ inf0, const float* __restrict__ inf1,
    const float* __restrict__ inf2, const float* __restrict__ anchors,
    const float* __restrict__ strides, const float* __restrict__ targets,
    float* __restrict__ ws)
{
    if (blockIdx.x < DBLOCKS) {
        // ---------------- dense obj baseline: 2048 scale-pure cells --------
        const int bi = blockIdx.x;
        const float* inf; int base; float w;
        if (bi < DB0)      { inf = inf0; base = bi * 2048;          w = 1.0f/(float)S0; }
        else if (bi < DB1) { inf = inf1; base = (bi - DB0) * 2048;  w = 1.0f/(float)S1; }
        else               { inf = inf2; base = (bi - DB1) * 2048;  w = 1.0f/(float)S2; }
        const int l0 = base + threadIdx.x;
        float v = 0.0f;
        #pragma unroll
        for (int k = 0; k < 8; ++k)
            v += softplusf(inf[(long)(l0 + k * 256) * 85 + 4]);
        #pragma unroll
        for (int off = 32; off > 0; off >>= 1) v += __shfl_down(v, off, 64);
        __shared__ float wsum[4];
        const int lane = threadIdx.x & 63, wid = threadIdx.x >> 6;
        if (lane == 0) wsum[wid] = v;
        __syncthreads();
        if (threadIdx.x == 0)
            ws[WS_OBJ + bi] = (wsum[0] + wsum[1] + wsum[2] + wsum[3]) * w;
    } else {
        // ---------------- target path: one wave per target -----------------
        const int tb   = blockIdx.x - DBLOCKS;
        const int wid  = threadIdx.x >> 6;
        const int lane = threadIdx.x & 63;
        const int t    = tb * 4 + wid;   // 0..511
        const int b    = t >> 5;

        const float x = targets[t*5+0];
        const float y = targets[t*5+1];
        const float w = targets[t*5+2];
        const float h = targets[t*5+3];
        const int cls = (int)targets[t*5+4];

        float acc[10];
        #pragma unroll
        for (int c = 0; c < 10; ++c) acc[c] = 0.0f;

        #pragma unroll
        for (int sa = 0; sa < 9; ++sa) {
            const int s = sa / 3;
            const int a = sa - 3 * s;
            const float st = strides[s];
            const float aw = anchors[(s*3+a)*2+0] / st;
            const float ah = anchors[(s*3+a)*2+1] / st;

            int ci, cj; float fx, fy, tbw, tbh;
            const bool hit = anchor_hit(x, y, w, h, st, aw, ah,
                                        ci, cj, fx, fy, tbw, tbh);
            if (hit) {  // wave-uniform
                const int g = (s == 0) ? 64 : (s == 1) ? 32 : 16;
                const float* inf = (s == 0) ? inf0 : (s == 1) ? inf1 : inf2;
                const float invM = (s == 0) ? 1.0f/(float)S0
                                 : (s == 1) ? 1.0f/(float)S1 : 1.0f/(float)S2;

                const int cellflat = ((b*3 + a)*g + cj)*g + ci;
                const float* pred = inf + (long)cellflat * 85;

                // box term (redundant across lanes; broadcast loads)
                const float p4 = pred[4];
                const float px = 1.0f / (1.0f + __expf(-pred[0]));
                const float py = 1.0f / (1.0f + __expf(-pred[1]));
                const float pw = fminf(__expf(pred[2]), 1000.0f) * aw;
                const float ph = fminf(__expf(pred[3]), 1000.0f) * ah;
                const float tx0 = fx - tbw*0.5f, ty0 = fy - tbh*0.5f;
                const float tx1 = fx + tbw*0.5f, ty1 = fy + tbh*0.5f;
                const float bx0 = px - pw*0.5f, by0 = py - ph*0.5f;
                const float bx1 = px + pw*0.5f, by1 = py + ph*0.5f;
                const float jx0 = fmaxf(bx0, tx0), jy0 = fmaxf(by0, ty0);
                const float jx1 = fminf(bx1, tx1), jy1 = fminf(by1, ty1);
                float inter2 = (jx1-jx0)*(jy1-jy0);
                inter2 = (jx0 < jx1 && jy0 < jy1) ? inter2 : 0.0f;
                const float iou2 = inter2 / (pw*ph + tbw*tbh - inter2);

                // cls term: lanes split the 80 classes (lane, lane+64)
                float v = softplusf(pred[5 + lane]);
                if (lane == cls) v -= pred[5 + cls];
                if (lane < 16) {
                    const int c2 = 64 + lane;
                    v += softplusf(pred[5 + c2]);
                    if (c2 == cls) v -= pred[5 + c2];
                }
                #pragma unroll
                for (int off = 32; off > 0; off >>= 1)
                    v += __shfl_down(v, off, 64);

                // t_obj dedupe: claim iff NO earlier target t'<t in this batch
                // hits the same (ci,cj) at this (s,a). Lanes 0..31 test
                // t'=b*32+lane with the bit-exact same anchor_hit.
                bool dup = false;
                if (lane < (t & 31)) {
                    const int t2 = (b << 5) + lane;
                    const float x2 = targets[t2*5+0];
                    const float y2 = targets[t2*5+1];
                    const float w2 = targets[t2*5+2];
                    const float h2 = targets[t2*5+3];
                    int ci2, cj2; float fx2, fy2, tbw2, tbh2;
                    const bool hit2 = anchor_hit(x2, y2, w2, h2, st, aw, ah,
                                                 ci2, cj2, fx2, fy2, tbw2, tbh2);
                    dup = hit2 && (ci2 == ci) && (cj2 == cj);
                }
                const unsigned long long m = __ballot(dup);

                acc[1 + s] += 1.0f;
                acc[4 + s] += 1.0f - iou2;
                acc[7 + s] += v;           // lane 0 holds the reduced value
                if (m == 0ull) acc[0] += -p4 * invM;
            }
        }

        // combine the 4 waves' rows (lane 0 of each holds valid acc)
        __shared__ float rows[4][10];
        if (lane == 0) {
            #pragma unroll
            for (int c = 0; c < 10; ++c) rows[wid][c] = acc[c];
        }
        __syncthreads();
        if (threadIdx.x < 10)
            ws[tb * 10 + threadIdx.x] = rows[0][threadIdx.x] +
                rows[1][threadIdx.x] + rows[2][threadIdx.x] +
                rows[3][threadIdx.x];
    }
}

// K2: reduce all block partials and emit the scalar loss.
__global__ __launch_bounds__(256) void yolo_finalize_kernel(
    const float* __restrict__ ws, float* __restrict__ out)
{
    float acc[10];
    #pragma unroll
    for (int c = 0; c < 10; ++c) acc[c] = 0.0f;
    for (int r = threadIdx.x; r < TBLOCKS; r += 256) {
        #pragma unroll
        for (int c = 0; c < 10; ++c) acc[c] += ws[r * 10 + c];
    }
    float obj = 0.0f;
    for (int i = threadIdx.x; i < DBLOCKS; i += 256) obj += ws[WS_OBJ + i];
    acc[0] += obj;

    #pragma unroll
    for (int c = 0; c < 10; ++c) {
        float v = acc[c];
        #pragma unroll
        for (int off = 32; off > 0; off >>= 1) v += __shfl_down(v, off, 64);
        acc[c] = v;
    }
    __shared__ float red[4][10];
    const int lane = threadIdx.x & 63, wid = threadIdx.x >> 6;
    if (lane == 0) {
        #pragma unroll
        for (int c = 0; c < 10; ++c) red[wid][c] = acc[c];
    }
    __syncthreads();
    if (threadIdx.x == 0) {
        float tt[10];
        #pragma unroll
        for (int c = 0; c < 10; ++c)
            tt[c] = red[0][c] + red[1][c] + red[2][c] + red[3][c];
        float box = 0.0f, cls = 0.0f;
        #pragma unroll
        for (int s = 0; s < 3; ++s) {
            const float cnt = fmaxf(tt[1 + s], 1.0f);
            box += tt[4 + s] / cnt;
            cls += tt[7 + s] / (cnt * 80.0f);
        }
        out[0] = 3.54f * box + 64.3f * tt[0] + 37.4f * cls;
    }
}

extern "C" void kernel_launch(void* const* d_in, const int* in_sizes, int n_in,
                              void* d_out, int out_size, void* d_ws, size_t ws_size,
                              hipStream_t stream) {
    const float* inf0    = (const float*)d_in[0];
    const float* inf1    = (const float*)d_in[1];
    const float* inf2    = (const float*)d_in[2];
    const float* anchors = (const float*)d_in[3];
    const float* strides = (const float*)d_in[4];
    const float* targets = (const float*)d_in[5];
    float* ws  = (float*)d_ws;
    float* out = (float*)d_out;

    yolo_main_kernel<<<DBLOCKS + TBLOCKS, 256, 0, stream>>>(
        inf0, inf1, inf2, anchors, strides, targets, ws);
    yolo_finalize_kernel<<<1, 256, 0, stream>>>(ws, out);
}